// Round 13
// baseline (718.716 us; speedup 1.0000x reference)
//
#include <hip/hip_runtime.h>

// Guided filter r=8 (K=17), eps=0.1, (8,3,1024,1024); f32 in / f32 out.
// V4: split-pass LDS (26.9 KB, pair-interleaved), occupancy 3->4+ blocks/CU.
//
// Per 32x32 output tile (256 threads), ONE arena [48 rows][140 words] f32
// holding (q0,q1) PAIRS per col (stride 140 = 12 mod 32 -> 2-way banks):
//   A  : vertical 17-tap sliding sums; write (sI,sP) pairs; keep (sIp,sII)
//        in 24 regs                                   [12 b64 writes]
//   B1a: horizontal 17-sums of (sI,sP) -> hI,hP in 24 regs [14 b128 reads]
//   A2 : write (sIp,sII) pairs over arena             [12 b64 writes]
//   B1b: horizontal 17-sums of (sIp,sII) + fold -> a,b    [14 b128 reads]
//   AB : write (a,b) pairs                            [6 b128 writes]
//   B2 : horizontal 17-sums of (a,b) -> hsA,hsB           [12 b128 reads]
//   HS : write (hsA,hsB) pairs                        [4 b128 writes]
//   C  : vertical 17-tap sliding sums + finale            [20 b64 reads]
// B-phase map: vr=(tid&15)+16*(tid>>6), u4=(tid>>4)&3 (rows vary per 16-lane
// group -> start banks 12*vr mod 32 = 8 quads x 2 = minimal).

#define TW 32
#define TH 32
#define AR 48                      // arena rows
#define SW 140                     // words per row (544 B)
#define SW2 70                     // float2 stride
#define SW4 35                     // float4 stride
#define INV_AREA (1.0f / 289.0f)
#define EPS 0.1f

__device__ __forceinline__ int refl1024(int v) {
    v = (v < 0) ? -v : v;
    v = (v > 1023) ? 2046 - v : v;
    if (v < 0) v = 0;
    if (v > 1023) v = 1023;
    return v;
}

__global__ __launch_bounds__(256, 4) void gf_fused(
    const float* __restrict__ P, const float* __restrict__ I,
    float* __restrict__ O, int H, int W)
{
    __shared__ __align__(16) float S[AR * SW];   // 26880 B
    float2* __restrict__ S2 = (float2*)S;
    float4* __restrict__ S4 = (float4*)S;

    const int tid = threadIdx.x;
    const int tx0 = blockIdx.x * TW;
    const int ty0 = blockIdx.y * TH;
    const size_t plane = (size_t)blockIdx.z * H * W;
    const float* __restrict__ Ic = I + plane;
    const float* __restrict__ Pc = P + plane;

    // ---------------- Phase A: vertical sliding sums ------------------------
    const int vc = tid & 63;                                   // vs col
    const int ck = __builtin_amdgcn_readfirstlane(tid >> 6);   // wave-uniform
    const int r0 = ck * 12;
    float ss2[12], ss3[12];                                    // (sIp,sII) regs
    {
        const int gx = refl1024(tx0 + vc - 16);
        float vI[28], vP[28];
        #pragma unroll
        for (int j = 0; j < 28; ++j) {
            const int gy = refl1024(ty0 + r0 - 16 + j);        // scalar
            const float* __restrict__ rI = Ic + (size_t)gy * W;
            const float* __restrict__ rP = Pc + (size_t)gy * W;
            vI[j] = rI[gx];
            vP[j] = rP[gx];
        }
        float s0 = 0.f, s1 = 0.f, s2 = 0.f, s3 = 0.f;
        #pragma unroll
        for (int j = 0; j < 17; ++j) {
            s0 += vI[j]; s1 += vP[j];
            s2 += vI[j] * vP[j];
            s3 += vI[j] * vI[j];
        }
        S2[r0 * SW2 + vc] = make_float2(s0, s1);
        ss2[0] = s2; ss3[0] = s3;
        #pragma unroll
        for (int o = 1; o < 12; ++o) {
            const float ni = vI[o + 16], oi = vI[o - 1];
            const float np_ = vP[o + 16], op_ = vP[o - 1];
            s0 += ni - oi;
            s1 += np_ - op_;
            s2 += ni * np_ - oi * op_;
            s3 += ni * ni - oi * oi;
            S2[(r0 + o) * SW2 + vc] = make_float2(s0, s1);
            ss2[o] = s2; ss3[o] = s3;
        }
    }
    __syncthreads();

    // ---------------- Phase B1a: horizontal sums of (sI,sP) -----------------
    const int vr = (tid & 15) + ((tid >> 6) << 4);   // 0..47 for tid<192
    const int u4 = (tid >> 4) & 3;                   // col-block (12 ab cols)
    float hI[12], hP[12];
    if (tid < 192) {
        float q0[28], q1[28];
        #pragma unroll
        for (int t = 0; t < 14; ++t) {
            const float4 w = S4[vr * SW4 + u4 * 6 + t];
            q0[2 * t] = w.x; q1[2 * t] = w.y;
            q0[2 * t + 1] = w.z; q1[2 * t + 1] = w.w;
        }
        float a0 = 0.f, a1 = 0.f;
        #pragma unroll
        for (int j = 0; j < 17; ++j) { a0 += q0[j]; a1 += q1[j]; }
        hI[0] = a0; hP[0] = a1;
        #pragma unroll
        for (int o = 1; o < 12; ++o) {
            a0 += q0[o + 16] - q0[o - 1];
            a1 += q1[o + 16] - q1[o - 1];
            hI[o] = a0; hP[o] = a1;
        }
    }
    __syncthreads();

    // ---------------- Phase A2: write (sIp,sII) pairs -----------------------
    #pragma unroll
    for (int o = 0; o < 12; ++o)
        S2[(r0 + o) * SW2 + vc] = make_float2(ss2[o], ss3[o]);
    __syncthreads();

    // ---------------- Phase B1b: horizontal sums of (sIp,sII) -> a,b --------
    float oa[12], ob[12];
    if (tid < 192) {
        float q0[28], q1[28];
        #pragma unroll
        for (int t = 0; t < 14; ++t) {
            const float4 w = S4[vr * SW4 + u4 * 6 + t];
            q0[2 * t] = w.x; q1[2 * t] = w.y;
            q0[2 * t + 1] = w.z; q1[2 * t + 1] = w.w;
        }
        float a0 = 0.f, a1 = 0.f;
        #pragma unroll
        for (int j = 0; j < 17; ++j) { a0 += q0[j]; a1 += q1[j]; }
        #pragma unroll
        for (int o = 0; o < 12; ++o) {
            if (o) {
                a0 += q0[o + 16] - q0[o - 1];
                a1 += q1[o + 16] - q1[o - 1];
            }
            const float mI  = hI[o] * INV_AREA;
            const float mP  = hP[o] * INV_AREA;
            const float mIp = a0 * INV_AREA;
            const float mII = a1 * INV_AREA;
            const float cov = mIp - mI * mP;
            const float var = mII - mI * mI;
            const float av  = cov / (var + EPS);
            oa[o] = av;
            ob[o] = mP - av * mI;
        }
    }
    __syncthreads();

    // ---------------- write (a,b) pairs -------------------------------------
    if (tid < 192) {
        #pragma unroll
        for (int t = 0; t < 6; ++t)
            S4[vr * SW4 + u4 * 6 + t] =
                make_float4(oa[2 * t], ob[2 * t], oa[2 * t + 1], ob[2 * t + 1]);
    }
    __syncthreads();

    // ---------------- Phase B2: horizontal sums of (a,b) --------------------
    float hsA[8], hsB[8];
    if (tid < 192) {
        float qa[24], qb[24];
        #pragma unroll
        for (int t = 0; t < 12; ++t) {
            const float4 w = S4[vr * SW4 + u4 * 4 + t];
            qa[2 * t] = w.x; qb[2 * t] = w.y;
            qa[2 * t + 1] = w.z; qb[2 * t + 1] = w.w;
        }
        float sa = 0.f, sb = 0.f;
        #pragma unroll
        for (int j = 0; j < 17; ++j) { sa += qa[j]; sb += qb[j]; }
        hsA[0] = sa; hsB[0] = sb;
        #pragma unroll
        for (int o = 1; o < 8; ++o) {
            sa += qa[o + 16] - qa[o - 1];
            sb += qb[o + 16] - qb[o - 1];
            hsA[o] = sa; hsB[o] = sb;
        }
    }
    __syncthreads();

    // ---------------- write (hsA,hsB) pairs ---------------------------------
    if (tid < 192) {
        #pragma unroll
        for (int t = 0; t < 4; ++t)
            S4[vr * SW4 + u4 * 4 + t] =
                make_float4(hsA[2 * t], hsB[2 * t], hsA[2 * t + 1], hsB[2 * t + 1]);
    }
    __syncthreads();

    // ---------------- Phase C: vertical sums + finale -----------------------
    {
        const int ox  = tid & 31;
        const int oy0 = (tid >> 5) * 4;    // 0,4,...,28
        float ca[20], cb[20];
        #pragma unroll
        for (int j = 0; j < 20; ++j) {
            const float2 w = S2[(oy0 + j) * SW2 + ox];
            ca[j] = w.x; cb[j] = w.y;
        }
        float sa = 0.f, sb = 0.f;
        #pragma unroll
        for (int j = 0; j < 17; ++j) { sa += ca[j]; sb += cb[j]; }
        #pragma unroll
        for (int o = 0; o < 4; ++o) {
            if (o) {
                sa += ca[o + 16] - ca[o - 1];
                sb += cb[o + 16] - cb[o - 1];
            }
            const size_t gp = (size_t)(ty0 + oy0 + o) * W + (tx0 + ox);
            O[plane + gp] = sa * INV_AREA * Ic[gp] + sb * INV_AREA;
        }
    }
}

extern "C" void kernel_launch(void* const* d_in, const int* in_sizes, int n_in,
                              void* d_out, int out_size, void* d_ws, size_t ws_size,
                              hipStream_t stream) {
    const int H = 1024, W = 1024;
    if (n_in < 2) return;
    const long long npx = (long long)H * W;
    const long long n0 = in_sizes[0];
    if (n0 <= 0 || (n0 % npx) != 0) return;
    if ((long long)out_size != n0) return;
    if (in_sizes[1] != in_sizes[0]) return;
    const int NP = (int)(n0 / npx);

    const float* p = (const float*)d_in[0];   // input_img
    const float* I = (const float*)d_in[1];   // guide_img
    float* out = (float*)d_out;

    dim3 grid(W / TW, H / TH, NP);
    gf_fused<<<grid, 256, 0, stream>>>(p, I, out, H, W);
}

// Round 14
// 204.871 us; speedup vs baseline: 3.5081x; 3.5081x over previous
//
#include <hip/hip_runtime.h>

// Guided filter r=8 (K=17), eps=0.1, (8,3,1024,1024); f32 in / f32 out.
// V5 = V4 split-pass WITHOUT the VGPR-strangling launch_bounds min-wave arg.
// (R13 post-mortem: __launch_bounds__(256,4) forced VGPR=64 -> massive scratch
// spills, 2.5 GB HBM traffic. Live-state audit: ~115 regs peak -> fits 128.)
//
// Per 32x32 output tile (256 threads), ONE arena [48 rows][140 words] f32
// (26.9 KB; 4-6 blocks/CU if VGPR<=128) holding (q0,q1) PAIRS per col:
//   A  : vertical 17-tap sliding sums; write (sI,sP) pairs; keep (sIp,sII)
//        in 24 regs                                   [12 b64 writes]
//   B1a: horizontal 17-sums of (sI,sP) -> hI,hP in 24 regs [14 b128 reads]
//   A2 : write (sIp,sII) pairs over arena             [12 b64 writes]
//   B1b: horizontal 17-sums of (sIp,sII) + fold -> a,b    [14 b128 reads]
//   AB : write (a,b) pairs                            [6 b128 writes]
//   B2 : horizontal 17-sums of (a,b) -> hsA,hsB           [12 b128 reads]
//   HS : write (hsA,hsB) pairs                        [4 b128 writes]
//   C  : vertical 17-tap sliding sums + finale            [20 b64 reads]

#define TW 32
#define TH 32
#define AR 48                      // arena rows
#define SW 140                     // words per row (544 B)
#define SW2 70                     // float2 stride
#define SW4 35                     // float4 stride
#define INV_AREA (1.0f / 289.0f)
#define EPS 0.1f

__device__ __forceinline__ int refl1024(int v) {
    v = (v < 0) ? -v : v;
    v = (v > 1023) ? 2046 - v : v;
    if (v < 0) v = 0;
    if (v > 1023) v = 1023;
    return v;
}

__global__ __launch_bounds__(256) void gf_fused(
    const float* __restrict__ P, const float* __restrict__ I,
    float* __restrict__ O, int H, int W)
{
    __shared__ __align__(16) float S[AR * SW];   // 26880 B
    float2* __restrict__ S2 = (float2*)S;
    float4* __restrict__ S4 = (float4*)S;

    const int tid = threadIdx.x;
    const int tx0 = blockIdx.x * TW;
    const int ty0 = blockIdx.y * TH;
    const size_t plane = (size_t)blockIdx.z * H * W;
    const float* __restrict__ Ic = I + plane;
    const float* __restrict__ Pc = P + plane;

    // ---------------- Phase A: vertical sliding sums ------------------------
    const int vc = tid & 63;                                   // vs col
    const int ck = __builtin_amdgcn_readfirstlane(tid >> 6);   // wave-uniform
    const int r0 = ck * 12;
    float ss2[12], ss3[12];                                    // (sIp,sII) regs
    {
        const int gx = refl1024(tx0 + vc - 16);
        float vI[28], vP[28];
        #pragma unroll
        for (int j = 0; j < 28; ++j) {
            const int gy = refl1024(ty0 + r0 - 16 + j);        // scalar
            const float* __restrict__ rI = Ic + (size_t)gy * W;
            const float* __restrict__ rP = Pc + (size_t)gy * W;
            vI[j] = rI[gx];
            vP[j] = rP[gx];
        }
        float s0 = 0.f, s1 = 0.f, s2 = 0.f, s3 = 0.f;
        #pragma unroll
        for (int j = 0; j < 17; ++j) {
            s0 += vI[j]; s1 += vP[j];
            s2 += vI[j] * vP[j];
            s3 += vI[j] * vI[j];
        }
        S2[r0 * SW2 + vc] = make_float2(s0, s1);
        ss2[0] = s2; ss3[0] = s3;
        #pragma unroll
        for (int o = 1; o < 12; ++o) {
            const float ni = vI[o + 16], oi = vI[o - 1];
            const float np_ = vP[o + 16], op_ = vP[o - 1];
            s0 += ni - oi;
            s1 += np_ - op_;
            s2 += ni * np_ - oi * op_;
            s3 += ni * ni - oi * oi;
            S2[(r0 + o) * SW2 + vc] = make_float2(s0, s1);
            ss2[o] = s2; ss3[o] = s3;
        }
    }
    __syncthreads();

    // ---------------- Phase B1a: horizontal sums of (sI,sP) -----------------
    const int vr = (tid & 15) + ((tid >> 6) << 4);   // 0..47 for tid<192
    const int u4 = (tid >> 4) & 3;                   // col-block (12 ab cols)
    float hI[12], hP[12];
    if (tid < 192) {
        float q0[28], q1[28];
        #pragma unroll
        for (int t = 0; t < 14; ++t) {
            const float4 w = S4[vr * SW4 + u4 * 6 + t];
            q0[2 * t] = w.x; q1[2 * t] = w.y;
            q0[2 * t + 1] = w.z; q1[2 * t + 1] = w.w;
        }
        float a0 = 0.f, a1 = 0.f;
        #pragma unroll
        for (int j = 0; j < 17; ++j) { a0 += q0[j]; a1 += q1[j]; }
        hI[0] = a0; hP[0] = a1;
        #pragma unroll
        for (int o = 1; o < 12; ++o) {
            a0 += q0[o + 16] - q0[o - 1];
            a1 += q1[o + 16] - q1[o - 1];
            hI[o] = a0; hP[o] = a1;
        }
    }
    __syncthreads();

    // ---------------- Phase A2: write (sIp,sII) pairs -----------------------
    #pragma unroll
    for (int o = 0; o < 12; ++o)
        S2[(r0 + o) * SW2 + vc] = make_float2(ss2[o], ss3[o]);
    __syncthreads();

    // ---------------- Phase B1b: horizontal sums of (sIp,sII) -> a,b --------
    float oa[12], ob[12];
    if (tid < 192) {
        float q0[28], q1[28];
        #pragma unroll
        for (int t = 0; t < 14; ++t) {
            const float4 w = S4[vr * SW4 + u4 * 6 + t];
            q0[2 * t] = w.x; q1[2 * t] = w.y;
            q0[2 * t + 1] = w.z; q1[2 * t + 1] = w.w;
        }
        float a0 = 0.f, a1 = 0.f;
        #pragma unroll
        for (int j = 0; j < 17; ++j) { a0 += q0[j]; a1 += q1[j]; }
        #pragma unroll
        for (int o = 0; o < 12; ++o) {
            if (o) {
                a0 += q0[o + 16] - q0[o - 1];
                a1 += q1[o + 16] - q1[o - 1];
            }
            const float mI  = hI[o] * INV_AREA;
            const float mP  = hP[o] * INV_AREA;
            const float mIp = a0 * INV_AREA;
            const float mII = a1 * INV_AREA;
            const float cov = mIp - mI * mP;
            const float var = mII - mI * mI;
            const float av  = cov / (var + EPS);
            oa[o] = av;
            ob[o] = mP - av * mI;
        }
    }
    __syncthreads();

    // ---------------- write (a,b) pairs -------------------------------------
    if (tid < 192) {
        #pragma unroll
        for (int t = 0; t < 6; ++t)
            S4[vr * SW4 + u4 * 6 + t] =
                make_float4(oa[2 * t], ob[2 * t], oa[2 * t + 1], ob[2 * t + 1]);
    }
    __syncthreads();

    // ---------------- Phase B2: horizontal sums of (a,b) --------------------
    float hsA[8], hsB[8];
    if (tid < 192) {
        float qa[24], qb[24];
        #pragma unroll
        for (int t = 0; t < 12; ++t) {
            const float4 w = S4[vr * SW4 + u4 * 4 + t];
            qa[2 * t] = w.x; qb[2 * t] = w.y;
            qa[2 * t + 1] = w.z; qb[2 * t + 1] = w.w;
        }
        float sa = 0.f, sb = 0.f;
        #pragma unroll
        for (int j = 0; j < 17; ++j) { sa += qa[j]; sb += qb[j]; }
        hsA[0] = sa; hsB[0] = sb;
        #pragma unroll
        for (int o = 1; o < 8; ++o) {
            sa += qa[o + 16] - qa[o - 1];
            sb += qb[o + 16] - qb[o - 1];
            hsA[o] = sa; hsB[o] = sb;
        }
    }
    __syncthreads();

    // ---------------- write (hsA,hsB) pairs ---------------------------------
    if (tid < 192) {
        #pragma unroll
        for (int t = 0; t < 4; ++t)
            S4[vr * SW4 + u4 * 4 + t] =
                make_float4(hsA[2 * t], hsB[2 * t], hsA[2 * t + 1], hsB[2 * t + 1]);
    }
    __syncthreads();

    // ---------------- Phase C: vertical sums + finale -----------------------
    {
        const int ox  = tid & 31;
        const int oy0 = (tid >> 5) * 4;    // 0,4,...,28
        float ca[20], cb[20];
        #pragma unroll
        for (int j = 0; j < 20; ++j) {
            const float2 w = S2[(oy0 + j) * SW2 + ox];
            ca[j] = w.x; cb[j] = w.y;
        }
        float sa = 0.f, sb = 0.f;
        #pragma unroll
        for (int j = 0; j < 17; ++j) { sa += ca[j]; sb += cb[j]; }
        #pragma unroll
        for (int o = 0; o < 4; ++o) {
            if (o) {
                sa += ca[o + 16] - ca[o - 1];
                sb += cb[o + 16] - cb[o - 1];
            }
            const size_t gp = (size_t)(ty0 + oy0 + o) * W + (tx0 + ox);
            O[plane + gp] = sa * INV_AREA * Ic[gp] + sb * INV_AREA;
        }
    }
}

extern "C" void kernel_launch(void* const* d_in, const int* in_sizes, int n_in,
                              void* d_out, int out_size, void* d_ws, size_t ws_size,
                              hipStream_t stream) {
    const int H = 1024, W = 1024;
    if (n_in < 2) return;
    const long long npx = (long long)H * W;
    const long long n0 = in_sizes[0];
    if (n0 <= 0 || (n0 % npx) != 0) return;
    if ((long long)out_size != n0) return;
    if (in_sizes[1] != in_sizes[0]) return;
    const int NP = (int)(n0 / npx);

    const float* p = (const float*)d_in[0];   // input_img
    const float* I = (const float*)d_in[1];   // guide_img
    float* out = (float*)d_out;

    dim3 grid(W / TW, H / TH, NP);
    gf_fused<<<grid, 256, 0, stream>>>(p, I, out, H, W);
}